// Round 1
// baseline (860.605 us; speedup 1.0000x reference)
//
#include <hip/hip_runtime.h>
#include <math.h>
#include <limits.h>

#define B 64
#define D 1024
#define MAXK 20
#define NSEG 8
#define NT 128   // j-tile per block in scoring kernel
#define KC 64    // k chunk staged in LDS

#define IDX_SENT 0x7FFFFFFF
#define NEG_INF (-INFINITY)

__device__ __forceinline__ bool better(float av, int ai, float bv, int bi) {
    // strict total order: higher score wins, tie -> lower index (matches jax.lax.top_k)
    return (av > bv) || (av == bv && ai < bi);
}

// ---------------- kernel 1: normalize z_ego -> ws.egoN [64][1024] ----------------
__global__ __launch_bounds__(256) void k_norm_ego(const float* __restrict__ ego,
                                                  float* __restrict__ egoN) {
    const int b = blockIdx.x, t = threadIdx.x;
    float4 v = *(const float4*)(ego + (size_t)b * D + t * 4);
    float s = v.x * v.x + v.y * v.y + v.z * v.z + v.w * v.w;
#pragma unroll
    for (int m = 1; m < 64; m <<= 1) s += __shfl_xor(s, m);
    __shared__ float p[4];
    if ((t & 63) == 0) p[t >> 6] = s;
    __syncthreads();
    float tot = p[0] + p[1] + p[2] + p[3];
    float dnm = fmaxf(sqrtf(tot), 1e-12f);
    float4 o;
    o.x = v.x / dnm; o.y = v.y / dnm; o.z = v.z / dnm; o.w = v.w / dnm;
    *(float4*)(egoN + (size_t)b * D + t * 4) = o;
}

// ---------------- kernel 2: scores[64][N] = 0.5*cos_sim + 0.5*sim_vt ----------------
// Block: 256 threads, tile M=64 x NT=128, K staged in chunks of 64.
__global__ __launch_bounds__(256) void k_scores(const float* __restrict__ exo,
                                                const float* __restrict__ egoN,
                                                const float* __restrict__ svt,
                                                float* __restrict__ scores, int N) {
    __shared__ __align__(16) float eg[64 * 68];    // ego chunk, stride 68 (pad)
    __shared__ __align__(16) float ex[128 * 64];   // exo chunk, XOR-swizzled 16B units
    __shared__ float nrm[128];

    const int t = threadIdx.x;
    const int jb = blockIdx.x * NT;
    const int tx = t & 15;   // j group: j0 = tx*8
    const int ty = t >> 4;   // m group: m0 = ty*4
    const int rr = t >> 4, cc = t & 15;  // staging row/col16

    float acc[4][8];
#pragma unroll
    for (int m = 0; m < 4; ++m)
#pragma unroll
        for (int i = 0; i < 8; ++i) acc[m][i] = 0.0f;
    float ssq[8] = {0, 0, 0, 0, 0, 0, 0, 0};

    for (int kc = 0; kc < D; kc += KC) {
        __syncthreads();
        // stage ego chunk: 64 rows x 64 cols
#pragma unroll
        for (int r = 0; r < 4; ++r) {
            int m = rr + 16 * r;
            float4 v = *(const float4*)(egoN + (size_t)m * D + kc + cc * 4);
            *(float4*)(eg + m * 68 + cc * 4) = v;
        }
        // stage exo chunk: 128 rows x 64 cols, accumulate sum-of-squares
#pragma unroll
        for (int r = 0; r < 8; ++r) {
            int j = rr + 16 * r;
            int jj = jb + j;
            float4 v = make_float4(0.f, 0.f, 0.f, 0.f);
            if (jj < N) v = *(const float4*)(exo + (size_t)jj * D + kc + cc * 4);
            ssq[r] += v.x * v.x + v.y * v.y + v.z * v.z + v.w * v.w;
            int cs = cc ^ ((j >> 3) & 7);
            *(float4*)(ex + (j << 6) + (cs << 2)) = v;
        }
        __syncthreads();

        const float* egp = eg + ty * 4 * 68;
#pragma unroll 4
        for (int k4 = 0; k4 < 16; ++k4) {
            float4 a0 = *(const float4*)(egp + 0 * 68 + k4 * 4);
            float4 a1 = *(const float4*)(egp + 1 * 68 + k4 * 4);
            float4 a2 = *(const float4*)(egp + 2 * 68 + k4 * 4);
            float4 a3 = *(const float4*)(egp + 3 * 68 + k4 * 4);
            int ko = (k4 ^ (tx & 7)) << 2;
#pragma unroll
            for (int i = 0; i < 8; ++i) {
                float4 e = *(const float4*)(ex + ((tx * 8 + i) << 6) + ko);
                acc[0][i] += a0.x * e.x; acc[0][i] += a0.y * e.y;
                acc[0][i] += a0.z * e.z; acc[0][i] += a0.w * e.w;
                acc[1][i] += a1.x * e.x; acc[1][i] += a1.y * e.y;
                acc[1][i] += a1.z * e.z; acc[1][i] += a1.w * e.w;
                acc[2][i] += a2.x * e.x; acc[2][i] += a2.y * e.y;
                acc[2][i] += a2.z * e.z; acc[2][i] += a2.w * e.w;
                acc[3][i] += a3.x * e.x; acc[3][i] += a3.y * e.y;
                acc[3][i] += a3.z * e.z; acc[3][i] += a3.w * e.w;
            }
        }
    }

    // reduce exo row sum-of-squares across the 16 lanes sharing each row
#pragma unroll
    for (int r = 0; r < 8; ++r) {
        float s = ssq[r];
        s += __shfl_xor(s, 1); s += __shfl_xor(s, 2);
        s += __shfl_xor(s, 4); s += __shfl_xor(s, 8);
        if (cc == 0) nrm[rr + 16 * r] = s;
    }
    __syncthreads();

    // epilogue: score = 0.5*dot/||exo_j|| + 0.5*svt[j]
#pragma unroll
    for (int i = 0; i < 8; ++i) {
        int j = tx * 8 + i;
        int jj = jb + j;
        if (jj < N) {
            float dn = fmaxf(sqrtf(nrm[j]), 1e-12f);
            float sv = 0.5f * svt[jj];
#pragma unroll
            for (int m = 0; m < 4; ++m) {
                float sc = 0.5f * (acc[m][i] / dn) + sv;
                scores[(size_t)(ty * 4 + m) * N + jj] = sc;
            }
        }
    }
}

// ---------------- kernel 3: per-(row,segment) top-20 ----------------
__global__ __launch_bounds__(256) void k_topk_scan(const float* __restrict__ scores,
                                                   float2* __restrict__ cand, int N) {
    const int row = blockIdx.x >> 3;
    const int seg = blockIdx.x & 7;
    const int t = threadIdx.x;
    const int seglen = (N + NSEG - 1) / NSEG;
    const int start = seg * seglen;
    const int end = (start + seglen < N) ? (start + seglen) : N;
    const float* rs = scores + (size_t)row * N;

    float lv[20]; int li[20];
#pragma unroll
    for (int p = 0; p < 20; ++p) { lv[p] = NEG_INF; li[p] = IDX_SENT; }

    for (int j = start + t; j < end; j += 256) {
        float s = rs[j];
        if (s > lv[19] || (s == lv[19] && j < li[19])) {
            float cv = s; int ci = j;
#pragma unroll
            for (int p = 0; p < 20; ++p) {
                bool bb = (cv > lv[p]) || (cv == lv[p] && ci < li[p]);
                float tv = lv[p]; int ti = li[p];
                lv[p] = bb ? cv : tv; li[p] = bb ? ci : ti;
                cv = bb ? tv : cv;   ci = bb ? ti : ci;
            }
        }
    }

    // wave-level merge: 20 rounds of argmax+pop over lane heads
    __shared__ float2 wc[4 * 20];
    const int lane = t & 63, w = t >> 6;
#pragma unroll 1
    for (int r = 0; r < 20; ++r) {
        float bv = lv[0]; int bi = li[0];
#pragma unroll
        for (int m = 1; m < 64; m <<= 1) {
            float ov = __shfl_xor(bv, m); int oi = __shfl_xor(bi, m);
            if (better(ov, oi, bv, bi)) { bv = ov; bi = oi; }
        }
        if (lv[0] == bv && li[0] == bi) {  // owner pops
#pragma unroll
            for (int p = 0; p < 19; ++p) { lv[p] = lv[p + 1]; li[p] = li[p + 1]; }
            lv[19] = NEG_INF; li[19] = IDX_SENT;
        }
        if (lane == 0) wc[w * 20 + r] = make_float2(bv, __int_as_float(bi));
    }
    __syncthreads();

    // block-level merge by wave 0 over 80 candidates
    if (w == 0) {
        float mv[2]; int mi[2];
        float2 c0 = (lane < 80) ? wc[lane]
                                : make_float2(NEG_INF, __int_as_float(IDX_SENT));
        float2 c1 = (lane + 64 < 80) ? wc[lane + 64]
                                     : make_float2(NEG_INF, __int_as_float(IDX_SENT));
        mv[0] = c0.x; mi[0] = __float_as_int(c0.y);
        mv[1] = c1.x; mi[1] = __float_as_int(c1.y);
        if (better(mv[1], mi[1], mv[0], mi[0])) {
            float tv = mv[0]; int ti = mi[0];
            mv[0] = mv[1]; mi[0] = mi[1]; mv[1] = tv; mi[1] = ti;
        }
#pragma unroll 1
        for (int r = 0; r < 20; ++r) {
            float bv = mv[0]; int bi = mi[0];
#pragma unroll
            for (int m = 1; m < 64; m <<= 1) {
                float ov = __shfl_xor(bv, m); int oi = __shfl_xor(bi, m);
                if (better(ov, oi, bv, bi)) { bv = ov; bi = oi; }
            }
            if (mv[0] == bv && mi[0] == bi) {
                mv[0] = mv[1]; mi[0] = mi[1];
                mv[1] = NEG_INF; mi[1] = IDX_SENT;
            }
            if (lane == 0)
                cand[((size_t)row * NSEG + seg) * 20 + r] = make_float2(bv, __int_as_float(bi));
        }
    }
}

// ---------------- kernel 4: final merge (160 cands/row -> top-20) ----------------
__global__ __launch_bounds__(64) void k_topk_final(const float2* __restrict__ cand,
                                                   int* __restrict__ idxi,
                                                   float* __restrict__ outIdx) {
    const int row = blockIdx.x;
    const int lane = threadIdx.x;
    const float2* c = cand + (size_t)row * NSEG * 20;  // 160 entries

    float mv[3]; int mi[3];
#pragma unroll
    for (int s = 0; s < 3; ++s) { mv[s] = NEG_INF; mi[s] = IDX_SENT; }
#pragma unroll
    for (int s = 0; s < 3; ++s) {
        int ci = lane + 64 * s;
        if (ci < 160) { float2 cc = c[ci]; mv[s] = cc.x; mi[s] = __float_as_int(cc.y); }
    }
    // sort 3 (network 01,12,01)
    {
        float tv; int ti;
        if (better(mv[1], mi[1], mv[0], mi[0])) { tv = mv[0]; ti = mi[0]; mv[0] = mv[1]; mi[0] = mi[1]; mv[1] = tv; mi[1] = ti; }
        if (better(mv[2], mi[2], mv[1], mi[1])) { tv = mv[1]; ti = mi[1]; mv[1] = mv[2]; mi[1] = mi[2]; mv[2] = tv; mi[2] = ti; }
        if (better(mv[1], mi[1], mv[0], mi[0])) { tv = mv[0]; ti = mi[0]; mv[0] = mv[1]; mi[0] = mi[1]; mv[1] = tv; mi[1] = ti; }
    }
#pragma unroll 1
    for (int r = 0; r < 20; ++r) {
        float bv = mv[0]; int bi = mi[0];
#pragma unroll
        for (int m = 1; m < 64; m <<= 1) {
            float ov = __shfl_xor(bv, m); int oi = __shfl_xor(bi, m);
            if (better(ov, oi, bv, bi)) { bv = ov; bi = oi; }
        }
        if (mv[0] == bv && mi[0] == bi) {
            mv[0] = mv[1]; mi[0] = mi[1];
            mv[1] = mv[2]; mi[1] = mi[2];
            mv[2] = NEG_INF; mi[2] = IDX_SENT;
        }
        if (lane == 0) {
            idxi[row * 20 + r] = bi;
            outIdx[row * 20 + r] = (float)bi;  // topk_idx as float in d_out tail
        }
    }
}

// ---------------- kernel 5: gather z_exo = exo_bank[topk_idx] ----------------
__global__ __launch_bounds__(256) void k_gather(const float* __restrict__ exo,
                                                const int* __restrict__ idxi,
                                                float* __restrict__ out) {
    const int b = blockIdx.x / MAXK, s = blockIdx.x % MAXK;
    const int idx = idxi[b * MAXK + s];
    const float4* src = (const float4*)(exo + (size_t)idx * D);
    float4* dst = (float4*)(out + (size_t)(b * MAXK + s) * D);
    dst[threadIdx.x] = src[threadIdx.x];
}

extern "C" void kernel_launch(void* const* d_in, const int* in_sizes, int n_in,
                              void* d_out, int out_size, void* d_ws, size_t ws_size,
                              hipStream_t stream) {
    (void)n_in; (void)out_size; (void)ws_size;
    const float* ego = (const float*)d_in[0];
    const float* exo = (const float*)d_in[1];
    // d_in[2] is k (==20, == MAX_K); top-20 hardcoded, out_size confirms k_eff=20
    const float* svt = (const float*)d_in[3];
    const int N = in_sizes[1] / D;  // 100000

    float* ws = (float*)d_ws;
    float* egoN = ws;                                   // 64*1024 floats
    float* scores = ws + (size_t)B * D;                 // 64*N floats
    float2* cand = (float2*)(scores + (size_t)B * N);   // 64*8*20 float2
    int* idxi = (int*)(cand + B * NSEG * 20);           // 64*20 int

    float* out = (float*)d_out;
    float* outIdx = out + (size_t)B * MAXK * D;         // idx tail (as float)

    k_norm_ego<<<B, 256, 0, stream>>>(ego, egoN);
    const int nblk = (N + NT - 1) / NT;
    k_scores<<<nblk, 256, 0, stream>>>(exo, egoN, svt, scores, N);
    k_topk_scan<<<B * NSEG, 256, 0, stream>>>(scores, cand, N);
    k_topk_final<<<B, 64, 0, stream>>>(cand, idxi, outIdx);
    k_gather<<<B * MAXK, 256, 0, stream>>>(exo, idxi, out);
}

// Round 3
// 766.616 us; speedup vs baseline: 1.1226x; 1.1226x over previous
//
#include <hip/hip_runtime.h>
#include <math.h>

#define B 64
#define D 1024
#define MAXK 20
#define NSEG 8
#define NT 128          // j-tile per block
#define KC 32           // k chunk staged in LDS
#define EXSTRIDE 132    // ex row stride (NT+4 floats)
#define EGSTRIDE 68     // eg row stride (64+4 floats)

#define IDX_SENT 0x7FFFFFFF
#define NEG_INF (-INFINITY)

__device__ __forceinline__ bool better(float av, int ai, float bv, int bi) {
    return (av > bv) || (av == bv && ai < bi);  // jax.lax.top_k order
}

// ---------------- kernel 1: normalize z_ego -> ws.egoN [64][1024] ----------------
__global__ __launch_bounds__(256) void k_norm_ego(const float* __restrict__ ego,
                                                  float* __restrict__ egoN) {
    const int b = blockIdx.x, t = threadIdx.x;
    float4 v = *(const float4*)(ego + (size_t)b * D + t * 4);
    float s = v.x * v.x + v.y * v.y + v.z * v.z + v.w * v.w;
#pragma unroll
    for (int m = 1; m < 64; m <<= 1) s += __shfl_xor(s, m);
    __shared__ float p[4];
    if ((t & 63) == 0) p[t >> 6] = s;
    __syncthreads();
    float tot = p[0] + p[1] + p[2] + p[3];
    float dnm = fmaxf(sqrtf(tot), 1e-12f);
    float4 o;
    o.x = v.x / dnm; o.y = v.y / dnm; o.z = v.z / dnm; o.w = v.w / dnm;
    *(float4*)(egoN + (size_t)b * D + t * 4) = o;
}

// ---------------- kernel 2: scores[64][N] = 0.5*cos + 0.5*svt ----------------
// 256 threads, tile 64m x 128j, K in chunks of 32 staged transposed in LDS.
// Per-thread: 8m x 4j float4 accumulators; register-prefetched staging.
__global__ __launch_bounds__(256, 4) void k_scores(const float* __restrict__ exo,
                                                   const float* __restrict__ egoN,
                                                   const float* __restrict__ svt,
                                                   float* __restrict__ scores, int N) {
    __shared__ __align__(16) float ex[KC * EXSTRIDE];  // [k][j] transposed exo tile
    __shared__ __align__(16) float eg[KC * EGSTRIDE];  // [k][m] transposed ego tile
    __shared__ float nrm[NT];

    const int t = threadIdx.x;
    const int jb = blockIdx.x * NT;
    const int tx = t & 31;      // j0 = tx*4
    const int ty = t >> 5;      // m0 = ty*8
    const int jr = t >> 3;      // staging row 0..31
    const int kq = t & 7;       // staging k-float4 0..7

    float4 acc[8];
#pragma unroll
    for (int m = 0; m < 8; ++m) acc[m] = make_float4(0.f, 0.f, 0.f, 0.f);
    float ssq[4] = {0.f, 0.f, 0.f, 0.f};

    float4 pe[4], pg[2];

    const float4* ex4 = (const float4*)ex;
    const float4* eg4 = (const float4*)eg;

    // prologue: load chunk 0 into registers
    {
        const int kc = 0;
#pragma unroll
        for (int q = 0; q < 4; ++q) {
            int j = jb + jr + 32 * q;
            pe[q] = (j < N) ? *(const float4*)(exo + (size_t)j * D + kc + kq * 4)
                            : make_float4(0.f, 0.f, 0.f, 0.f);
        }
#pragma unroll
        for (int p2 = 0; p2 < 2; ++p2) {
            int m = jr + 32 * p2;
            pg[p2] = *(const float4*)(egoN + (size_t)m * D + kc + kq * 4);
        }
    }

    for (int c = 0; c < D / KC; ++c) {
        __syncthreads();
        // ---- stage registers -> LDS (transposed), accumulate exo sum-of-squares
#pragma unroll
        for (int q = 0; q < 4; ++q) {
            ssq[q] += pe[q].x * pe[q].x + pe[q].y * pe[q].y +
                      pe[q].z * pe[q].z + pe[q].w * pe[q].w;
            int jl = jr + 32 * q;
            ex[(kq * 4 + 0) * EXSTRIDE + jl] = pe[q].x;
            ex[(kq * 4 + 1) * EXSTRIDE + jl] = pe[q].y;
            ex[(kq * 4 + 2) * EXSTRIDE + jl] = pe[q].z;
            ex[(kq * 4 + 3) * EXSTRIDE + jl] = pe[q].w;
        }
#pragma unroll
        for (int p2 = 0; p2 < 2; ++p2) {
            int ml = jr + 32 * p2;
            eg[(kq * 4 + 0) * EGSTRIDE + ml] = pg[p2].x;
            eg[(kq * 4 + 1) * EGSTRIDE + ml] = pg[p2].y;
            eg[(kq * 4 + 2) * EGSTRIDE + ml] = pg[p2].z;
            eg[(kq * 4 + 3) * EGSTRIDE + ml] = pg[p2].w;
        }
        __syncthreads();
        // ---- prefetch next chunk into registers (latency hides under compute)
        if (c + 1 < D / KC) {
            const int kc = (c + 1) * KC;
#pragma unroll
            for (int q = 0; q < 4; ++q) {
                int j = jb + jr + 32 * q;
                pe[q] = (j < N) ? *(const float4*)(exo + (size_t)j * D + kc + kq * 4)
                                : make_float4(0.f, 0.f, 0.f, 0.f);
            }
#pragma unroll
            for (int p2 = 0; p2 < 2; ++p2) {
                int m = jr + 32 * p2;
                pg[p2] = *(const float4*)(egoN + (size_t)m * D + kc + kq * 4);
            }
        }
        // ---- compute 32 k-steps from LDS
#pragma unroll 8
        for (int k = 0; k < KC; ++k) {
            float4 e  = ex4[k * (EXSTRIDE / 4) + tx];
            float4 a0 = eg4[k * (EGSTRIDE / 4) + (ty << 1)];
            float4 a1 = eg4[k * (EGSTRIDE / 4) + (ty << 1) + 1];
            acc[0].x += a0.x * e.x; acc[0].y += a0.x * e.y; acc[0].z += a0.x * e.z; acc[0].w += a0.x * e.w;
            acc[1].x += a0.y * e.x; acc[1].y += a0.y * e.y; acc[1].z += a0.y * e.z; acc[1].w += a0.y * e.w;
            acc[2].x += a0.z * e.x; acc[2].y += a0.z * e.y; acc[2].z += a0.z * e.z; acc[2].w += a0.z * e.w;
            acc[3].x += a0.w * e.x; acc[3].y += a0.w * e.y; acc[3].z += a0.w * e.z; acc[3].w += a0.w * e.w;
            acc[4].x += a1.x * e.x; acc[4].y += a1.x * e.y; acc[4].z += a1.x * e.z; acc[4].w += a1.x * e.w;
            acc[5].x += a1.y * e.x; acc[5].y += a1.y * e.y; acc[5].z += a1.y * e.z; acc[5].w += a1.y * e.w;
            acc[6].x += a1.z * e.x; acc[6].y += a1.z * e.y; acc[6].z += a1.z * e.z; acc[6].w += a1.z * e.w;
            acc[7].x += a1.w * e.x; acc[7].y += a1.w * e.y; acc[7].z += a1.w * e.z; acc[7].w += a1.w * e.w;
        }
    }

    // exo row norms: reduce ssq across the 8 lanes sharing each j
#pragma unroll
    for (int q = 0; q < 4; ++q) {
        float s = ssq[q];
        s += __shfl_xor(s, 1); s += __shfl_xor(s, 2); s += __shfl_xor(s, 4);
        if (kq == 0) nrm[jr + 32 * q] = s;
    }
    __syncthreads();

    const int j0 = jb + tx * 4;
    float4 nr = ((const float4*)nrm)[tx];
    if (j0 + 3 < N) {
        float4 sv4 = *(const float4*)(svt + j0);
        float dnx = fmaxf(sqrtf(nr.x), 1e-12f);
        float dny = fmaxf(sqrtf(nr.y), 1e-12f);
        float dnz = fmaxf(sqrtf(nr.z), 1e-12f);
        float dnw = fmaxf(sqrtf(nr.w), 1e-12f);
#pragma unroll
        for (int mm = 0; mm < 8; ++mm) {
            int row = ty * 8 + mm;
            float4 sc;
            sc.x = 0.5f * (acc[mm].x / dnx) + 0.5f * sv4.x;
            sc.y = 0.5f * (acc[mm].y / dny) + 0.5f * sv4.y;
            sc.z = 0.5f * (acc[mm].z / dnz) + 0.5f * sv4.z;
            sc.w = 0.5f * (acc[mm].w / dnw) + 0.5f * sv4.w;
            *(float4*)(scores + (size_t)row * N + j0) = sc;
        }
    } else if (j0 < N) {
        // partial tail (unused when N%4==0, kept for safety)
        float dn[4] = {fmaxf(sqrtf(nr.x), 1e-12f), fmaxf(sqrtf(nr.y), 1e-12f),
                       fmaxf(sqrtf(nr.z), 1e-12f), fmaxf(sqrtf(nr.w), 1e-12f)};
#pragma unroll
        for (int mm = 0; mm < 8; ++mm) {
            int row = ty * 8 + mm;
            if (j0 + 0 < N) scores[(size_t)row * N + j0 + 0] = 0.5f * (acc[mm].x / dn[0]) + 0.5f * svt[j0 + 0];
            if (j0 + 1 < N) scores[(size_t)row * N + j0 + 1] = 0.5f * (acc[mm].y / dn[1]) + 0.5f * svt[j0 + 1];
            if (j0 + 2 < N) scores[(size_t)row * N + j0 + 2] = 0.5f * (acc[mm].z / dn[2]) + 0.5f * svt[j0 + 2];
            if (j0 + 3 < N) scores[(size_t)row * N + j0 + 3] = 0.5f * (acc[mm].w / dn[3]) + 0.5f * svt[j0 + 3];
        }
    }
}

// ---------------- kernel 3: per-(row,segment) top-20 ----------------
__global__ __launch_bounds__(256) void k_topk_scan(const float* __restrict__ scores,
                                                   float2* __restrict__ cand, int N) {
    const int row = blockIdx.x >> 3;
    const int seg = blockIdx.x & 7;
    const int t = threadIdx.x;
    int seglen = (N + NSEG - 1) / NSEG;
    seglen = (seglen + 3) & ~3;
    const int start = seg * seglen;
    const int end = (start + seglen < N) ? (start + seglen) : N;
    const float* rs = scores + (size_t)row * N;

    float lv[20]; int li[20];
#pragma unroll
    for (int p = 0; p < 20; ++p) { lv[p] = NEG_INF; li[p] = IDX_SENT; }

#define TK_INSERT(SVAL, JIDX)                                                     \
    if ((SVAL) > lv[19] || ((SVAL) == lv[19] && (JIDX) < li[19])) {               \
        float cv = (SVAL); int ci = (JIDX);                                       \
        _Pragma("unroll")                                                         \
        for (int p = 0; p < 20; ++p) {                                            \
            bool bb = (cv > lv[p]) || (cv == lv[p] && ci < li[p]);                \
            float tv = lv[p]; int ti = li[p];                                     \
            lv[p] = bb ? cv : tv; li[p] = bb ? ci : ti;                           \
            cv = bb ? tv : cv;   ci = bb ? ti : ci;                               \
        }                                                                         \
    }

    if (start < end) {
        const int end4 = end & ~3;
        const float4* rs4 = (const float4*)rs;
        for (int jf = (start >> 2) + t; jf < (end4 >> 2); jf += 256) {
            float4 f = rs4[jf];
            int j0 = jf << 2;
            TK_INSERT(f.x, j0);
            TK_INSERT(f.y, j0 + 1);
            TK_INSERT(f.z, j0 + 2);
            TK_INSERT(f.w, j0 + 3);
        }
        if (t < end - end4) {
            int j = end4 + t;
            float s = rs[j];
            TK_INSERT(s, j);
        }
    }
#undef TK_INSERT

    // wave-level merge: 20 rounds of argmax+pop over lane heads
    __shared__ float2 wc[4 * 20];
    const int lane = t & 63, w = t >> 6;
#pragma unroll 1
    for (int r = 0; r < 20; ++r) {
        float bv = lv[0]; int bi = li[0];
#pragma unroll
        for (int m = 1; m < 64; m <<= 1) {
            float ov = __shfl_xor(bv, m); int oi = __shfl_xor(bi, m);
            if (better(ov, oi, bv, bi)) { bv = ov; bi = oi; }
        }
        if (lv[0] == bv && li[0] == bi) {  // owner pops
#pragma unroll
            for (int p = 0; p < 19; ++p) { lv[p] = lv[p + 1]; li[p] = li[p + 1]; }
            lv[19] = NEG_INF; li[19] = IDX_SENT;
        }
        if (lane == 0) wc[w * 20 + r] = make_float2(bv, __int_as_float(bi));
    }
    __syncthreads();

    // block-level merge by wave 0 over 80 candidates
    if (w == 0) {
        float mv[2]; int mi[2];
        float2 c0 = (lane < 80) ? wc[lane]
                                : make_float2(NEG_INF, __int_as_float(IDX_SENT));
        float2 c1 = (lane + 64 < 80) ? wc[lane + 64]
                                     : make_float2(NEG_INF, __int_as_float(IDX_SENT));
        mv[0] = c0.x; mi[0] = __float_as_int(c0.y);
        mv[1] = c1.x; mi[1] = __float_as_int(c1.y);
        if (better(mv[1], mi[1], mv[0], mi[0])) {
            float tv = mv[0]; int ti = mi[0];
            mv[0] = mv[1]; mi[0] = mi[1]; mv[1] = tv; mi[1] = ti;
        }
#pragma unroll 1
        for (int r = 0; r < 20; ++r) {
            float bv = mv[0]; int bi = mi[0];
#pragma unroll
            for (int m = 1; m < 64; m <<= 1) {
                float ov = __shfl_xor(bv, m); int oi = __shfl_xor(bi, m);
                if (better(ov, oi, bv, bi)) { bv = ov; bi = oi; }
            }
            if (mv[0] == bv && mi[0] == bi) {
                mv[0] = mv[1]; mi[0] = mi[1];
                mv[1] = NEG_INF; mi[1] = IDX_SENT;
            }
            if (lane == 0)
                cand[((size_t)row * NSEG + seg) * 20 + r] = make_float2(bv, __int_as_float(bi));
        }
    }
}

// ---------------- kernel 4: final merge (160 cands/row -> top-20) ----------------
__global__ __launch_bounds__(64) void k_topk_final(const float2* __restrict__ cand,
                                                   int* __restrict__ idxi,
                                                   float* __restrict__ outIdx) {
    const int row = blockIdx.x;
    const int lane = threadIdx.x;
    const float2* c = cand + (size_t)row * NSEG * 20;  // 160 entries

    float mv[3]; int mi[3];
#pragma unroll
    for (int s = 0; s < 3; ++s) { mv[s] = NEG_INF; mi[s] = IDX_SENT; }
#pragma unroll
    for (int s = 0; s < 3; ++s) {
        int ci = lane + 64 * s;
        if (ci < 160) { float2 cc = c[ci]; mv[s] = cc.x; mi[s] = __float_as_int(cc.y); }
    }
    {
        float tv; int ti;
        if (better(mv[1], mi[1], mv[0], mi[0])) { tv = mv[0]; ti = mi[0]; mv[0] = mv[1]; mi[0] = mi[1]; mv[1] = tv; mi[1] = ti; }
        if (better(mv[2], mi[2], mv[1], mi[1])) { tv = mv[1]; ti = mi[1]; mv[1] = mv[2]; mi[1] = mi[2]; mv[2] = tv; mi[2] = ti; }
        if (better(mv[1], mi[1], mv[0], mi[0])) { tv = mv[0]; ti = mi[0]; mv[0] = mv[1]; mi[0] = mi[1]; mv[1] = tv; mi[1] = ti; }
    }
#pragma unroll 1
    for (int r = 0; r < 20; ++r) {
        float bv = mv[0]; int bi = mi[0];
#pragma unroll
        for (int m = 1; m < 64; m <<= 1) {
            float ov = __shfl_xor(bv, m); int oi = __shfl_xor(bi, m);
            if (better(ov, oi, bv, bi)) { bv = ov; bi = oi; }
        }
        if (mv[0] == bv && mi[0] == bi) {
            mv[0] = mv[1]; mi[0] = mi[1];
            mv[1] = mv[2]; mi[1] = mi[2];
            mv[2] = NEG_INF; mi[2] = IDX_SENT;
        }
        if (lane == 0) {
            idxi[row * 20 + r] = bi;
            outIdx[row * 20 + r] = (float)bi;
        }
    }
}

// ---------------- kernel 5: gather z_exo = exo_bank[topk_idx] ----------------
__global__ __launch_bounds__(256) void k_gather(const float* __restrict__ exo,
                                                const int* __restrict__ idxi,
                                                float* __restrict__ out) {
    const int b = blockIdx.x / MAXK, s = blockIdx.x % MAXK;
    const int idx = idxi[b * MAXK + s];
    const float4* src = (const float4*)(exo + (size_t)idx * D);
    float4* dst = (float4*)(out + (size_t)(b * MAXK + s) * D);
    dst[threadIdx.x] = src[threadIdx.x];
}

extern "C" void kernel_launch(void* const* d_in, const int* in_sizes, int n_in,
                              void* d_out, int out_size, void* d_ws, size_t ws_size,
                              hipStream_t stream) {
    (void)n_in; (void)out_size; (void)ws_size;
    const float* ego = (const float*)d_in[0];
    const float* exo = (const float*)d_in[1];
    const float* svt = (const float*)d_in[3];
    const int N = in_sizes[1] / D;  // 100000

    float* ws = (float*)d_ws;
    float* egoN = ws;                                   // 64*1024
    float* scores = ws + (size_t)B * D;                 // 64*N
    float2* cand = (float2*)(scores + (size_t)B * N);   // 64*8*20 float2
    int* idxi = (int*)(cand + B * NSEG * 20);           // 64*20

    float* out = (float*)d_out;
    float* outIdx = out + (size_t)B * MAXK * D;

    k_norm_ego<<<B, 256, 0, stream>>>(ego, egoN);
    const int nblk = (N + NT - 1) / NT;
    k_scores<<<nblk, 256, 0, stream>>>(exo, egoN, svt, scores, N);
    k_topk_scan<<<B * NSEG, 256, 0, stream>>>(scores, cand, N);
    k_topk_final<<<B, 64, 0, stream>>>(cand, idxi, outIdx);
    k_gather<<<B * MAXK, 256, 0, stream>>>(exo, idxi, out);
}